// Round 15
// baseline (70.633 us; speedup 1.0000x reference)
//
#include <hip/hip_runtime.h>
#include <hip/hip_bf16.h>

#define LOG2E_F 1.4426950408889634f

typedef __attribute__((ext_vector_type(8))) short short8;
typedef __attribute__((ext_vector_type(4))) float f32x4;
typedef __attribute__((ext_vector_type(2))) float f32x2;

__device__ inline unsigned short f2b(float f) {
    __hip_bfloat16 h = __float2bfloat16(f);   // RNE
    return *reinterpret_cast<unsigned short*>(&h);
}

__device__ inline short8 load_frag_f32(const float* p) {
    const float4 lo = *(const float4*)p;
    const float4 hi = *(const float4*)(p + 4);
    short8 r;
    r[0] = (short)f2b(lo.x); r[1] = (short)f2b(lo.y);
    r[2] = (short)f2b(lo.z); r[3] = (short)f2b(lo.w);
    r[4] = (short)f2b(hi.x); r[5] = (short)f2b(hi.y);
    r[6] = (short)f2b(hi.z); r[7] = (short)f2b(hi.w);
    return r;
}

__device__ inline f32x2 mk2(float a, float b) { f32x2 r; r.x = a; r.y = b; return r; }

// =====================================================================
// Prologue: one-time f32 -> bf16 conversion of x, Win, Wout.
// =====================================================================
__global__ __launch_bounds__(256) void prep_kernel(
    const float* __restrict__ x, const float* __restrict__ Win,
    const float* __restrict__ Wout,
    unsigned short* __restrict__ xbf, unsigned short* __restrict__ winbf,
    unsigned short* __restrict__ woutbf)
{
    const int i = blockIdx.x * 256 + threadIdx.x;   // unit = 8 floats
    const float* src; unsigned short* dst; size_t off;
    if (i < 262144)       { src = x;    dst = xbf;    off = (size_t)i * 8; }
    else if (i < 268288)  { src = Win;  dst = winbf;  off = (size_t)(i - 262144) * 8; }
    else                  { src = Wout; dst = woutbf; off = (size_t)(i - 268288) * 8; }
    const short8 r = load_frag_f32(src + off);
    *(short8*)(dst + off) = r;
}

// =====================================================================
// Fused layer, MFMA attention. 512 blocks (1 system) x 256 thr (4 waves),
// LDS 61.5KB -> 2 blocks/CU.
//  Phase 1: QKV bf16-MFMA; Q,K -> LDS [atom][h*32+d] bf16 (upper 16 d
//           zeroed: K=32 MFMA padding); V -> LDS transposed [h][d][atom].
//  Phase 2: per wave 2 heads. S^T = mfma(K,Q) (swapped: q ends lane-major)
//           -> lattice exp2 per (q,k) pair (16 independent chains/lane)
//           -> p = exp2(st-16)*ssum -> den via 2 shfl_xor -> p bf16 via
//           wave-local LDS pscr -> O^T = mfma(V^T, P^T) -> agg bf16 LDS.
//  Phase 3: out-projection MFMA (R14 pattern).
// =====================================================================
__global__ __launch_bounds__(256, 2) void fused_mfma_kernel(
    const unsigned short* __restrict__ xbf, const unsigned short* __restrict__ winbf,
    const float* __restrict__ bin, const unsigned short* __restrict__ woutbf,
    const float* __restrict__ bout, const float* __restrict__ alpha,
    const float* __restrict__ dist2, float* __restrict__ out)
{
    __shared__ unsigned short Ql[32][264];     // 16.5 KB, stride 528B (16B-aligned)
    __shared__ unsigned short Kl[32][264];     // 16.5 KB
    __shared__ unsigned short Vt[8][16][40];   // 10.0 KB, V^T[h][d][atom]
    __shared__ unsigned short pscr[4][32][36]; //  9.0 KB, per-wave P scratch
    __shared__ float alpha_l[32][8];           //  1.0 KB
    __shared__ unsigned short aggl[32][136];   //  8.5 KB

    const int sys  = blockIdx.x;
    const int tid  = threadIdx.x;      // 0..255
    const int lane = tid & 63;
    const int wv   = tid >> 6;         // 0..3
    const int c16  = lane & 15;
    const int g    = lane >> 4;        // 0..3
    const int base = sys << 5;

    // zero the d=16..31 halves of Q/K rows (K=32 MFMA zero padding) + alpha
    {
        const int atom = tid >> 3;
        const int hh   = tid & 7;
        const uint4 z = {0, 0, 0, 0};
        *(uint4*)&Ql[atom][hh * 32 + 16] = z;
        *(uint4*)&Ql[atom][hh * 32 + 24] = z;
        *(uint4*)&Kl[atom][hh * 32 + 16] = z;
        *(uint4*)&Kl[atom][hh * 32 + 24] = z;
        alpha_l[atom][hh] = alpha[(size_t)(base + atom) * 8 + hh];
    }

    // ---------------- Phase 1: QKV projection into LDS ----------------
    short8 af[2][4];
    #pragma unroll
    for (int rt = 0; rt < 2; ++rt)
        #pragma unroll
        for (int ks = 0; ks < 4; ++ks)
            af[rt][ks] = *(const short8*)(
                xbf + (size_t)(base + rt * 16 + c16) * 128 + ks * 32 + g * 8);

    #pragma unroll
    for (int j = 0; j < 6; ++j) {
        const int ct = wv * 6 + j;            // 0..23 (wave-uniform)
        const int c  = ct * 16 + c16;         // global col 0..383
        short8 bf[4];
        #pragma unroll
        for (int ks = 0; ks < 4; ++ks)
            bf[ks] = *(const short8*)(winbf + (size_t)c * 128 + ks * 32 + g * 8);
        const float bias_v = bin[c];
        const int   bufi   = ct >> 3;         // 0=q, 1=k, 2=v
        const int   hh     = ct & 7;

        #pragma unroll
        for (int rt = 0; rt < 2; ++rt) {
            f32x4 acc = {0.f, 0.f, 0.f, 0.f};
            #pragma unroll
            for (int ks = 0; ks < 4; ++ks)
                acc = __builtin_amdgcn_mfma_f32_16x16x32_bf16(af[rt][ks], bf[ks], acc, 0, 0, 0);
            // D: col = lane&15 = feature-in-head, row = g*4+r = atom-in-tile
            #pragma unroll
            for (int r = 0; r < 4; ++r) {
                const int atom = rt * 16 + g * 4 + r;
                const float v  = acc[r] + bias_v;
                if (bufi == 0)
                    Ql[atom][hh * 32 + c16] = f2b(v * (0.25f * LOG2E_F));
                else if (bufi == 1)
                    Kl[atom][hh * 32 + c16] = f2b(v);
                else
                    Vt[hh][c16][atom] = f2b(v);   // V^T[h][d][k]
            }
        }
    }

    __syncthreads();

    // ---------------- Phase 2: MFMA attention (2 heads per wave) -------
    const f32x4 zero4 = {0.f, 0.f, 0.f, 0.f};
    #pragma unroll
    for (int hh2 = 0; hh2 < 2; ++hh2) {
        const int h = wv * 2 + hh2;

        // S^T = K * Q^T per head: A=K[key][d(32,zero-pad)], B[d][q]=Q[q][d]
        short8 kA0 = *(const short8*)&Kl[c16][h * 32 + g * 8];
        short8 kA1 = *(const short8*)&Kl[c16 + 16][h * 32 + g * 8];
        short8 qB0 = *(const short8*)&Ql[c16][h * 32 + g * 8];
        short8 qB1 = *(const short8*)&Ql[c16 + 16][h * 32 + g * 8];
        f32x4 st[2][2];
        st[0][0] = __builtin_amdgcn_mfma_f32_16x16x32_bf16(kA0, qB0, zero4, 0, 0, 0);
        st[0][1] = __builtin_amdgcn_mfma_f32_16x16x32_bf16(kA0, qB1, zero4, 0, 0, 0);
        st[1][0] = __builtin_amdgcn_mfma_f32_16x16x32_bf16(kA1, qB0, zero4, 0, 0, 0);
        st[1][1] = __builtin_amdgcn_mfma_f32_16x16x32_bf16(kA1, qB1, zero4, 0, 0, 0);
        // lane's pairs: q = c16 + 16*qt, key = g*4 + r + 16*kt

        const float al2q0 = alpha_l[c16][h] * LOG2E_F;        // < 0
        const float al2q1 = alpha_l[c16 + 16][h] * LOG2E_F;
        const float* bq0 = dist2 + ((size_t)(base + c16) * 32 + g * 4) * 16;
        const float* bq1 = dist2 + ((size_t)(base + c16 + 16) * 32 + g * 4) * 16;

        float p[2][2][4];
        float den0 = 0.f, den1 = 0.f;

        #pragma unroll
        for (int qt = 0; qt < 2; ++qt) {
            const float  al2  = qt ? al2q1 : al2q0;
            const f32x2  a2   = mk2(al2, al2);
            const float* bq   = qt ? bq1 : bq0;
            #pragma unroll
            for (int kt = 0; kt < 2; ++kt) {
                #pragma unroll
                for (int r = 0; r < 4; ++r) {
                    const float* dp = bq + (r + 16 * kt) * 16;   // row (q, k=g*4+r+16kt)
                    const float4 t0 = *(const float4*)(dp + 0);
                    const float4 t1 = *(const float4*)(dp + 4);
                    const float4 t2 = *(const float4*)(dp + 8);
                    const float4 t3 = *(const float4*)(dp + 12);
                    // ssum = sum_r exp2(al2*d2) — args in [-52,0], shift-free safe
                    const f32x2 d2p[8] = {mk2(t0.x,t0.y), mk2(t0.z,t0.w),
                                          mk2(t1.x,t1.y), mk2(t1.z,t1.w),
                                          mk2(t2.x,t2.y), mk2(t2.z,t2.w),
                                          mk2(t3.x,t3.y), mk2(t3.z,t3.w)};
                    f32x2 es;
                    {
                        const f32x2 a0 = a2 * d2p[0];
                        es = mk2(__builtin_amdgcn_exp2f(a0.x), __builtin_amdgcn_exp2f(a0.y));
                        #pragma unroll
                        for (int i = 1; i < 8; ++i) {
                            const f32x2 a = a2 * d2p[i];
                            es += mk2(__builtin_amdgcn_exp2f(a.x), __builtin_amdgcn_exp2f(a.y));
                        }
                    }
                    const float ssum = es.x + es.y;              // (0, 16]
                    const float pv = __builtin_amdgcn_exp2f(st[kt][qt][r] - 16.0f) * ssum;
                    p[kt][qt][r] = pv;
                    if (qt == 0) den0 += pv; else den1 += pv;
                }
            }
        }

        // den per q: reduce over lane groups g (keys)
        den0 += __shfl_xor(den0, 16); den0 += __shfl_xor(den0, 32);
        den1 += __shfl_xor(den1, 16); den1 += __shfl_xor(den1, 32);

        // pack p -> bf16 into wave-local pscr[q][k]
        #pragma unroll
        for (int qt = 0; qt < 2; ++qt) {
            const int q = c16 + 16 * qt;
            #pragma unroll
            for (int kt = 0; kt < 2; ++kt) {
                uint2 w;
                w.x = (unsigned)f2b(p[kt][qt][0]) | ((unsigned)f2b(p[kt][qt][1]) << 16);
                w.y = (unsigned)f2b(p[kt][qt][2]) | ((unsigned)f2b(p[kt][qt][3]) << 16);
                *(uint2*)&pscr[wv][q][kt * 16 + g * 4] = w;      // keys 4g..4g+3 (+16kt)
            }
        }

        // O^T = V^T * P^T  (K=32 keys exactly; wave-local LDS, no barrier)
        const short8 vA  = *(const short8*)&Vt[h][c16][g * 8];
        const short8 pB0 = *(const short8*)&pscr[wv][c16][g * 8];
        const short8 pB1 = *(const short8*)&pscr[wv][c16 + 16][g * 8];
        const f32x4 ov0 = __builtin_amdgcn_mfma_f32_16x16x32_bf16(vA, pB0, zero4, 0, 0, 0);
        const f32x4 ov1 = __builtin_amdgcn_mfma_f32_16x16x32_bf16(vA, pB1, zero4, 0, 0, 0);
        // D: col = c16 -> q, row = g*4+r -> d

        const float inv0 = 1.0f / den0;
        const float inv1 = 1.0f / den1;
        #pragma unroll
        for (int r = 0; r < 4; ++r) {
            aggl[c16][h * 16 + g * 4 + r]      = f2b(ov0[r] * inv0);
            aggl[c16 + 16][h * 16 + g * 4 + r] = f2b(ov1[r] * inv1);
        }
    }

    __syncthreads();

    // ---------------- Phase 3: out-projection --------------------------
    short8 aA[2][4];
    #pragma unroll
    for (int rt = 0; rt < 2; ++rt)
        #pragma unroll
        for (int ks = 0; ks < 4; ++ks)
            aA[rt][ks] = *(const short8*)&aggl[rt * 16 + c16][ks * 32 + g * 8];

    #pragma unroll
    for (int j = 0; j < 2; ++j) {
        const int ct = wv * 2 + j;            // 0..7
        const int c  = ct * 16 + c16;         // 0..127
        short8 bf[4];
        #pragma unroll
        for (int ks = 0; ks < 4; ++ks)
            bf[ks] = *(const short8*)(woutbf + (size_t)c * 128 + ks * 32 + g * 8);
        const float bias_v = bout[c];
        #pragma unroll
        for (int rt = 0; rt < 2; ++rt) {
            f32x4 oacc = {0.f, 0.f, 0.f, 0.f};
            #pragma unroll
            for (int ks = 0; ks < 4; ++ks)
                oacc = __builtin_amdgcn_mfma_f32_16x16x32_bf16(aA[rt][ks], bf[ks], oacc, 0, 0, 0);
            #pragma unroll
            for (int r = 0; r < 4; ++r) {
                const int row = base + rt * 16 + g * 4 + r;
                out[(size_t)row * 128 + c] = oacc[r] + bias_v;
            }
        }
    }
}

// =====================================================================
extern "C" void kernel_launch(void* const* d_in, const int* in_sizes, int n_in,
                              void* d_out, int out_size, void* d_ws, size_t ws_size,
                              hipStream_t stream)
{
    const float* x     = (const float*)d_in[0];   // [16384,128]
    const float* Win   = (const float*)d_in[1];   // [384,128]
    const float* bin   = (const float*)d_in[2];   // [384]
    const float* Wout  = (const float*)d_in[3];   // [128,128]
    const float* bout  = (const float*)d_in[4];   // [128]
    const float* alpha = (const float*)d_in[5];   // [16384,8]
    const float* dist2 = (const float*)d_in[6];   // [524288,16]

    unsigned short* xbf    = (unsigned short*)d_ws;            // 4 MB
    unsigned short* winbf  = xbf + (size_t)16384 * 128;        // 96 KB
    unsigned short* woutbf = winbf + (size_t)384 * 128;        // 32 KB

    prep_kernel<<<dim3(1056), 256, 0, stream>>>(x, Win, Wout, xbf, winbf, woutbf);
    fused_mfma_kernel<<<dim3(512), 256, 0, stream>>>(
        xbf, winbf, bin, woutbf, bout, alpha, dist2, (float*)d_out);
}

// Round 16
// 35.853 us; speedup vs baseline: 1.9701x; 1.9701x over previous
//
#include <hip/hip_runtime.h>
#include <hip/hip_bf16.h>

#define LOG2E_F 1.4426950408889634f

typedef __attribute__((ext_vector_type(8))) short short8;
typedef __attribute__((ext_vector_type(4))) float f32x4;
typedef __attribute__((ext_vector_type(2))) float f32x2;

__device__ inline unsigned short f2b(float f) {
    __hip_bfloat16 h = __float2bfloat16(f);   // RNE
    return *reinterpret_cast<unsigned short*>(&h);
}

__device__ inline short8 load_frag_f32(const float* p) {
    const float4 lo = *(const float4*)p;
    const float4 hi = *(const float4*)(p + 4);
    short8 r;
    r[0] = (short)f2b(lo.x); r[1] = (short)f2b(lo.y);
    r[2] = (short)f2b(lo.z); r[3] = (short)f2b(lo.w);
    r[4] = (short)f2b(hi.x); r[5] = (short)f2b(hi.y);
    r[6] = (short)f2b(hi.z); r[7] = (short)f2b(hi.w);
    return r;
}

__device__ inline f32x2 mk2(float a, float b) { f32x2 r; r.x = a; r.y = b; return r; }
__device__ inline f32x2 bfup(unsigned u) {
    return mk2(__uint_as_float(u << 16), __uint_as_float(u & 0xffff0000u));
}
#define PK_FMA(a, b, c) __builtin_elementwise_fma((a), (b), (c))

// =====================================================================
// Prologue: one-time f32 -> bf16 conversion of x, Win, Wout.
// =====================================================================
__global__ __launch_bounds__(256) void prep_kernel(
    const float* __restrict__ x, const float* __restrict__ Win,
    const float* __restrict__ Wout,
    unsigned short* __restrict__ xbf, unsigned short* __restrict__ winbf,
    unsigned short* __restrict__ woutbf)
{
    const int i = blockIdx.x * 256 + threadIdx.x;   // unit = 8 floats
    const float* src; unsigned short* dst; size_t off;
    if (i < 262144)       { src = x;    dst = xbf;    off = (size_t)i * 8; }
    else if (i < 268288)  { src = Win;  dst = winbf;  off = (size_t)(i - 262144) * 8; }
    else                  { src = Wout; dst = woutbf; off = (size_t)(i - 268288) * 8; }
    const short8 r = load_frag_f32(src + off);
    *(short8*)(dst + off) = r;
}

// =====================================================================
// Fused layer. R13/R14 base (256 blocks = 1/CU, 512 thr = 2 systems),
// R16 change: PV moved to the matrix pipe. Thread (qi,h) keeps the
// EXACT R13 dist2 walk (sequential rows, 8-thread broadcast share),
// computes p per kj, packs bf16 pairs into pw[16] (full unroll, static
// idx), writes P-row to LDS; after one barrier each wave computes
// O^T = mfma(V^T, P^T) per head and normalizes with LDS 1/den.
// Removes per-kj PV fma + V unpack + V LDS reads from the VALU path.
// =====================================================================
__global__ __launch_bounds__(512, 2) void fused2_kernel(
    const unsigned short* __restrict__ xbf, const unsigned short* __restrict__ winbf,
    const float* __restrict__ bin, const unsigned short* __restrict__ woutbf,
    const float* __restrict__ bout, const float* __restrict__ alpha,
    const float* __restrict__ dist2, float* __restrict__ out)
{
    __shared__ float          qf[2][32][164];      // 41.0 KB  q f32
    __shared__ unsigned short Kb[2][32][8][16];    // 16.0 KB  K bf16 rows
    __shared__ unsigned short Vt[2][8][16][40];    // 20.0 KB  V^T bf16 [h][d][atom]
    __shared__ unsigned short pscr[2][8][33][40];  // 41.2 KB  P bf16 [h][q][k] (+pads)
    __shared__ float          denl[2][8][33];      //  2.1 KB
    __shared__ unsigned short aggl[2][32][136];    // 17.0 KB

    const int tid  = threadIdx.x;                // 0..511
    const int grp  = tid >> 8;                   // system group 0/1
    const int t    = tid & 255;
    const int sys  = blockIdx.x * 2 + grp;
    const int lane = t & 63;
    const int wv   = t >> 6;                     // wave within group, 0..3
    const int r16  = lane & 15;
    const int kg   = lane >> 4;
    const int base = sys << 5;

    // ---------------- Phase 1: QKV projection into LDS[grp] ------------
    short8 af[2][4];
    #pragma unroll
    for (int rt = 0; rt < 2; ++rt)
        #pragma unroll
        for (int ks = 0; ks < 4; ++ks)
            af[rt][ks] = *(const short8*)(
                xbf + (size_t)(base + rt * 16 + r16) * 128 + ks * 32 + kg * 8);

    #pragma unroll
    for (int j = 0; j < 6; ++j) {
        const int ct = wv * 6 + j;            // 0..23 (wave-uniform)
        const int c  = ct * 16 + r16;         // global col 0..383
        short8 bf[4];
        #pragma unroll
        for (int ks = 0; ks < 4; ++ks)
            bf[ks] = *(const short8*)(winbf + (size_t)c * 128 + ks * 32 + kg * 8);
        const float bias_v = bin[c];
        const int   bufi   = ct >> 3;         // 0=q, 1=k, 2=v
        const int   hh     = ct & 7;

        #pragma unroll
        for (int rt = 0; rt < 2; ++rt) {
            f32x4 acc = {0.f, 0.f, 0.f, 0.f};
            #pragma unroll
            for (int ks = 0; ks < 4; ++ks)
                acc = __builtin_amdgcn_mfma_f32_16x16x32_bf16(af[rt][ks], bf[ks], acc, 0, 0, 0);
            // D: col = r16 = feature-in-head, row = kg*4+r = atom-in-tile
            #pragma unroll
            for (int r = 0; r < 4; ++r) {
                const int atom = rt * 16 + kg * 4 + r;
                const float v  = acc[r] + bias_v;
                if (bufi == 0)
                    qf[grp][atom][hh * 20 + r16] = v * (0.25f * LOG2E_F);
                else if (bufi == 1)
                    Kb[grp][atom][hh][r16] = f2b(v);
                else
                    Vt[grp][hh][r16][atom] = f2b(v);   // V^T[h][d][k]
            }
        }
    }

    const int qi = t >> 3;
    const int h  = t & 7;
    const float al2 = alpha[(size_t)(base + qi) * 8 + h] * LOG2E_F;   // < 0
    const f32x2 al22 = mk2(al2, al2);

    __syncthreads();

    // ---------------- Phase 2a: scores (dist2 walk identical to R13) ---
    f32x2 q2[8];
    {
        const float* qrow = &qf[grp][qi][h * 20];
        #pragma unroll
        for (int d4 = 0; d4 < 4; ++d4) {
            const float4 tq = *(const float4*)(qrow + (d4 << 2));
            q2[d4 * 2 + 0] = mk2(tq.x, tq.y);
            q2[d4 * 2 + 1] = mk2(tq.z, tq.w);
        }
    }

    float den = 0.f;
    unsigned pw[16];
    float plo = 0.f;
    const float* dp = dist2 + (size_t)(sys * 1024 + qi * 32) * 16;

    #pragma unroll
    for (int kj = 0; kj < 32; ++kj) {
        // lattice sum, shift-free (args al2*d2 in [-52,0]): R14-validated
        const float* dpk = dp + kj * 16;
        const float4 t0 = *(const float4*)(dpk + 0);
        const float4 t1 = *(const float4*)(dpk + 4);
        const float4 t2 = *(const float4*)(dpk + 8);
        const float4 t3 = *(const float4*)(dpk + 12);
        const f32x2 d2p[8] = {mk2(t0.x,t0.y), mk2(t0.z,t0.w), mk2(t1.x,t1.y), mk2(t1.z,t1.w),
                              mk2(t2.x,t2.y), mk2(t2.z,t2.w), mk2(t3.x,t3.y), mk2(t3.z,t3.w)};
        f32x2 es;
        {
            const f32x2 a0 = al22 * d2p[0];
            es = mk2(__builtin_amdgcn_exp2f(a0.x), __builtin_amdgcn_exp2f(a0.y));
            #pragma unroll
            for (int i = 1; i < 8; ++i) {
                const f32x2 a = al22 * d2p[i];
                es += mk2(__builtin_amdgcn_exp2f(a.x), __builtin_amdgcn_exp2f(a.y));
            }
        }
        const float ssum = es.x + es.y;              // (0, 16]

        // q.k dot: bf16 K row (2 x b128, 8-lane broadcast) unpacked
        const uint4 ka = *(const uint4*)&Kb[grp][kj][h][0];
        const uint4 kb = *(const uint4*)&Kb[grp][kj][h][8];
        f32x2 dA = q2[0] * bfup(ka.x);
        f32x2 dB = q2[1] * bfup(ka.y);
        dA = PK_FMA(q2[2], bfup(ka.z), dA);
        dB = PK_FMA(q2[3], bfup(ka.w), dB);
        dA = PK_FMA(q2[4], bfup(kb.x), dA);
        dB = PK_FMA(q2[5], bfup(kb.y), dB);
        dA = PK_FMA(q2[6], bfup(kb.z), dA);
        dB = PK_FMA(q2[7], bfup(kb.w), dB);
        const float dot = (dA.x + dA.y) + (dB.x + dB.y);   // log2-domain

        // fixed-shift softmax (R8-R14 validated)
        const float p = __builtin_amdgcn_exp2f(dot - 16.0f) * ssum;
        den += p;

        if ((kj & 1) == 0) {
            plo = p;
        } else {
            pw[kj >> 1] = (unsigned)f2b(plo) | ((unsigned)f2b(p) << 16);
        }
    }

    // write P row (32 bf16 = 4 x b128) and 1/den to LDS
    {
        unsigned short* pr = &pscr[grp][h][qi][0];
        *(uint4*)(pr + 0)  = *(uint4*)&pw[0];
        *(uint4*)(pr + 8)  = *(uint4*)&pw[4];
        *(uint4*)(pr + 16) = *(uint4*)&pw[8];
        *(uint4*)(pr + 24) = *(uint4*)&pw[12];
        denl[grp][h][qi] = 1.0f / den;
    }

    __syncthreads();

    // ---------------- Phase 2b: PV on the matrix pipe ------------------
    const f32x4 zero4 = {0.f, 0.f, 0.f, 0.f};
    #pragma unroll
    for (int hh2 = 0; hh2 < 2; ++hh2) {
        const int hh = wv * 2 + hh2;
        // A = V^T[h]: lane(row=d=r16, k-slice kg*8); B = P^T: lane(k-slice, col=q)
        const short8 vA  = *(const short8*)&Vt[grp][hh][r16][kg * 8];
        const short8 pB0 = *(const short8*)&pscr[grp][hh][r16][kg * 8];
        const short8 pB1 = *(const short8*)&pscr[grp][hh][r16 + 16][kg * 8];
        const f32x4 o0 = __builtin_amdgcn_mfma_f32_16x16x32_bf16(vA, pB0, zero4, 0, 0, 0);
        const f32x4 o1 = __builtin_amdgcn_mfma_f32_16x16x32_bf16(vA, pB1, zero4, 0, 0, 0);
        // D: col = r16 -> q, row = kg*4+r -> d
        const float inv0 = denl[grp][hh][r16];
        const float inv1 = denl[grp][hh][r16 + 16];
        uint2 w0, w1;
        w0.x = (unsigned)f2b(o0[0] * inv0) | ((unsigned)f2b(o0[1] * inv0) << 16);
        w0.y = (unsigned)f2b(o0[2] * inv0) | ((unsigned)f2b(o0[3] * inv0) << 16);
        w1.x = (unsigned)f2b(o1[0] * inv1) | ((unsigned)f2b(o1[1] * inv1) << 16);
        w1.y = (unsigned)f2b(o1[2] * inv1) | ((unsigned)f2b(o1[3] * inv1) << 16);
        *(uint2*)&aggl[grp][r16][hh * 16 + kg * 4]      = w0;
        *(uint2*)&aggl[grp][r16 + 16][hh * 16 + kg * 4] = w1;
    }

    __syncthreads();

    // ---------------- Phase 3: out-projection --------------------------
    short8 aA[2][4];
    #pragma unroll
    for (int rt = 0; rt < 2; ++rt)
        #pragma unroll
        for (int ks = 0; ks < 4; ++ks)
            aA[rt][ks] = *(const short8*)&aggl[grp][rt * 16 + r16][ks * 32 + kg * 8];

    #pragma unroll
    for (int j = 0; j < 2; ++j) {
        const int ct = wv * 2 + j;            // 0..7
        const int c  = ct * 16 + r16;         // 0..127
        short8 bf[4];
        #pragma unroll
        for (int ks = 0; ks < 4; ++ks)
            bf[ks] = *(const short8*)(woutbf + (size_t)c * 128 + ks * 32 + kg * 8);
        const float bias_v = bout[c];
        #pragma unroll
        for (int rt = 0; rt < 2; ++rt) {
            f32x4 oacc = {0.f, 0.f, 0.f, 0.f};
            #pragma unroll
            for (int ks = 0; ks < 4; ++ks)
                oacc = __builtin_amdgcn_mfma_f32_16x16x32_bf16(aA[rt][ks], bf[ks], oacc, 0, 0, 0);
            #pragma unroll
            for (int r = 0; r < 4; ++r) {
                const int row = base + rt * 16 + kg * 4 + r;
                out[(size_t)row * 128 + c] = oacc[r] + bias_v;
            }
        }
    }
}

// =====================================================================
extern "C" void kernel_launch(void* const* d_in, const int* in_sizes, int n_in,
                              void* d_out, int out_size, void* d_ws, size_t ws_size,
                              hipStream_t stream)
{
    const float* x     = (const float*)d_in[0];   // [16384,128]
    const float* Win   = (const float*)d_in[1];   // [384,128]
    const float* bin   = (const float*)d_in[2];   // [384]
    const float* Wout  = (const float*)d_in[3];   // [128,128]
    const float* bout  = (const float*)d_in[4];   // [128]
    const float* alpha = (const float*)d_in[5];   // [16384,8]
    const float* dist2 = (const float*)d_in[6];   // [524288,16]

    unsigned short* xbf    = (unsigned short*)d_ws;            // 4 MB
    unsigned short* winbf  = xbf + (size_t)16384 * 128;        // 96 KB
    unsigned short* woutbf = winbf + (size_t)384 * 128;        // 32 KB

    prep_kernel<<<dim3(1056), 256, 0, stream>>>(x, Win, Wout, xbf, winbf, woutbf);
    fused2_kernel<<<dim3(256), 512, 0, stream>>>(
        xbf, winbf, bin, woutbf, bout, alpha, dist2, (float*)d_out);
}